// Round 11
// baseline (297.660 us; speedup 1.0000x reference)
//
#include <hip/hip_runtime.h>
#include <math.h>

#define NN 4096
#define DD 512
#define FF 512
#define CAP 256
#define SCALE 0.08838834764831845f

typedef unsigned short u16;
typedef __attribute__((ext_vector_type(8))) short short8;
typedef __attribute__((ext_vector_type(8))) unsigned short ushort8;
typedef __attribute__((ext_vector_type(4))) unsigned short ushort4v;
typedef __attribute__((ext_vector_type(4))) float floatx4;

__device__ __forceinline__ float bf2f(u16 u) {
    union { unsigned int i; float f; } x; x.i = ((unsigned int)u) << 16; return x.f;
}
__device__ __forceinline__ u16 f2bf(float f) {
    union { float f; unsigned int i; } x; x.f = f;
    unsigned int r = (x.i + 0x7FFFu + ((x.i >> 16) & 1u)) >> 16;
    return (u16)r;
}
__device__ __forceinline__ void gld_lds16(const void* g, void* l) {
    __builtin_amdgcn_global_load_lds((const __attribute__((address_space(1))) void*)g,
                                     (__attribute__((address_space(3))) void*)l, 16, 0, 0);
}

// ---------------------------------------------------------------- setup: cast+bias (blocks 0..191) | idx build (192..4287)
struct SetupArgs {
    const float* w[6];
    const float* bq; const float* bk; const float* bv;
    const int* mask;
    u16* wc; float* bcat; int* idx; int* cnt;
};
__global__ void setup_kernel(SetupArgs a) {
    const int bid = blockIdx.x, t = threadIdx.x;
    if (bid < 192) {
        // --- weight cast (R3-proven mapping)
        int region = bid >> 4;
        int layer = region / 6, mat = region - layer * 6;
        const float* src = a.w[mat] + (size_t)layer * (DD * DD);
        u16* d = a.wc + (size_t)region * (DD * DD);
        int off = (bid & 15) * 16384 + t * 4;
#pragma unroll
        for (int i = 0; i < 16; i++) {
            int e = off + i * 1024;
            float4 f = *(const float4*)&src[e];
            ushort4v u;
            u.x = f2bf(f.x); u.y = f2bf(f.y); u.z = f2bf(f.z); u.w = f2bf(f.w);
            *(ushort4v*)&d[e] = u;
        }
        if (bid < 2) {   // bias concat for layer = bid
            int l = bid;
            for (int it = 0; it < 6; it++) {
                int j = it * 256 + t;
                int m = j >> 9, col = j & 511;
                const float* bp = (m == 0) ? a.bq : (m == 1) ? a.bk : a.bv;
                a.bcat[l * 1536 + j] = bp[l * DD + col];
            }
        }
    } else {
        // --- idx build, one row per block (R3-proven)
        int row = bid - 192;
        __shared__ int c;
        if (t == 0) c = 0;
        __syncthreads();
        const int4* mrow = (const int4*)(a.mask + (size_t)row * NN);
        for (int j4 = t; j4 < NN / 4; j4 += blockDim.x) {
            int4 m4 = mrow[j4];
            int base = j4 * 4;
            if (m4.x == 0) a.idx[row * CAP + atomicAdd(&c, 1)] = base;
            if (m4.y == 0) a.idx[row * CAP + atomicAdd(&c, 1)] = base + 1;
            if (m4.z == 0) a.idx[row * CAP + atomicAdd(&c, 1)] = base + 2;
            if (m4.w == 0) a.idx[row * CAP + atomicAdd(&c, 1)] = base + 3;
        }
        __syncthreads();
        if (t == 0) a.cnt[row] = (c < CAP) ? c : CAP;
    }
}

// ---------------------------------------------------------------- layernorm (fp32 in, bf16 out)
__global__ void ln_kernel(const float* __restrict__ x, const float* __restrict__ g,
                          const float* __restrict__ b, u16* __restrict__ out) {
    int wave = threadIdx.x >> 6, lane = threadIdx.x & 63;
    int row = blockIdx.x * 4 + wave;
    const float* xr = x + (size_t)row * DD;
    float4 p0 = *(const float4*)&xr[lane * 8];
    float4 p1 = *(const float4*)&xr[lane * 8 + 4];
    float v[8] = {p0.x, p0.y, p0.z, p0.w, p1.x, p1.y, p1.z, p1.w};
    float s = 0.f;
#pragma unroll
    for (int i = 0; i < 8; i++) s += v[i];
#pragma unroll
    for (int off = 32; off; off >>= 1) s += __shfl_xor(s, off);
    float mu = s * (1.0f / DD);
    float vs = 0.f;
#pragma unroll
    for (int i = 0; i < 8; i++) { float d = v[i] - mu; vs += d * d; }
#pragma unroll
    for (int off = 32; off; off >>= 1) vs += __shfl_xor(vs, off);
    float r = rsqrtf(vs * (1.0f / DD) + 1e-5f);
    float4 g0 = *(const float4*)&g[lane * 8];
    float4 g1 = *(const float4*)&g[lane * 8 + 4];
    float4 b0 = *(const float4*)&b[lane * 8];
    float4 b1 = *(const float4*)&b[lane * 8 + 4];
    float ge[8] = {g0.x, g0.y, g0.z, g0.w, g1.x, g1.y, g1.z, g1.w};
    float be[8] = {b0.x, b0.y, b0.z, b0.w, b1.x, b1.y, b1.z, b1.w};
    ushort8 ov;
#pragma unroll
    for (int i = 0; i < 8; i++) ov[i] = f2bf((v[i] - mu) * r * ge[i] + be[i]);
    *(ushort8*)&out[(size_t)row * DD + lane * 8] = ov;
}

// ---------------------------------------------------------------- 64x64 GEMM, BK=128
// LDS row-major 128 cols. Staging sub-block s in [0,4): row = m0+s*16+(t>>4), chunk t&15.
// LDS dest = As + s*2048 + t*8 (wave-contiguous: base + lane*16). 4 K-iters, 16 MFMA each.
// MODE 0: -> bf16; 1: gelu -> bf16; 2: resOut = resIn + val (fp32)
template <int MODE>
__launch_bounds__(256)
__global__ void gemm_bf16(const u16* __restrict__ A, const u16* __restrict__ B,
                          const float* __restrict__ bias, const float* __restrict__ resIn,
                          float* __restrict__ resOut, u16* __restrict__ outB,
                          int M, int Nout, int K) {
    __shared__ u16 As[64 * 128];   // 16 KB
    __shared__ u16 Bs[64 * 128];   // 16 KB
    const int m0 = blockIdx.y * 64, n0 = blockIdx.x * 64;
    const int t = threadIdx.x;
    const int wave = t >> 6, lane = t & 63;
    const int wm = (wave & 1) * 32, wn = (wave >> 1) * 32;
    const int sr = t >> 4, sc = (t & 15) * 8;     // staging row-in-16 / chunk
    const int fr = lane & 15, fq = (lane >> 4) * 8;

    floatx4 acc[2][2] = {};
    const u16* agp[4]; const u16* bgp[4];
    u16* asp[4]; u16* bsp[4];
#pragma unroll
    for (int s = 0; s < 4; s++) {
        agp[s] = A + (size_t)(m0 + s * 16 + sr) * K + sc;
        bgp[s] = B + (size_t)(n0 + s * 16 + sr) * K + sc;
        asp[s] = As + s * 2048 + t * 8;
        bsp[s] = Bs + s * 2048 + t * 8;
    }

    for (int k0 = 0; k0 < K; k0 += 128) {
        __syncthreads();
#pragma unroll
        for (int s = 0; s < 4; s++) {
            gld_lds16(agp[s] + k0, asp[s]);
            gld_lds16(bgp[s] + k0, bsp[s]);
        }
        __syncthreads();
#pragma unroll
        for (int h = 0; h < 4; h++) {
            short8 af[2], bf[2];
#pragma unroll
            for (int i = 0; i < 2; i++) af[i] = *(const short8*)&As[(wm + 16 * i + fr) * 128 + h * 32 + fq];
#pragma unroll
            for (int j = 0; j < 2; j++) bf[j] = *(const short8*)&Bs[(wn + 16 * j + fr) * 128 + h * 32 + fq];
#pragma unroll
            for (int i = 0; i < 2; i++)
#pragma unroll
                for (int j = 0; j < 2; j++)
                    acc[i][j] = __builtin_amdgcn_mfma_f32_16x16x32_bf16(af[i], bf[j], acc[i][j], 0, 0, 0);
        }
    }

    const int er = (lane >> 4) * 4, ec = lane & 15;
#pragma unroll
    for (int i = 0; i < 2; i++) {
#pragma unroll
        for (int j = 0; j < 2; j++) {
            int col = n0 + wn + 16 * j + ec;
            float bsv = bias[col];
#pragma unroll
            for (int r = 0; r < 4; r++) {
                int row = m0 + wm + 16 * i + er + r;
                float val = acc[i][j][r] + bsv;
                if (MODE == 1) val = 0.5f * val * (1.0f + erff(val * 0.70710678118654752f));
                if (MODE == 2) {
                    resOut[(size_t)row * Nout + col] = resIn[(size_t)row * Nout + col] + val;
                } else {
                    outB[(size_t)row * Nout + col] = f2bf(val);
                }
            }
        }
    }
}

// ---------------------------------------------------------------- 128x64 QKV GEMM, BK=64 (R10-proven)
__launch_bounds__(256)
__global__ void gemm_qkv(const u16* __restrict__ A, const u16* __restrict__ B,
                         const float* __restrict__ bias, u16* __restrict__ outB) {
    __shared__ u16 As[128 * 64];   // 16 KB
    __shared__ u16 Bs[64 * 64];    // 8 KB
    const int m0 = blockIdx.y * 128, n0 = blockIdx.x * 64;
    const int t = threadIdx.x;
    const int wave = t >> 6, lane = t & 63;
    const int wm = (wave & 1) * 64, wn = (wave >> 1) * 32;
    const int sr = t >> 3, sc = (t & 7) * 8;
    const int fr = lane & 15, fq = (lane >> 4) * 8;

    floatx4 acc[4][2] = {};
    const u16* agp[4];
    u16* asp[4];
#pragma unroll
    for (int u = 0; u < 4; u++) {
        agp[u] = A + (size_t)(m0 + 32 * u + sr) * DD + sc;
        asp[u] = As + u * (32 * 64) + t * 8;
    }
    const u16* bg0 = B + (size_t)(n0 + sr) * DD + sc;
    const u16* bg1 = B + (size_t)(n0 + 32 + sr) * DD + sc;
    u16* bs0 = Bs + t * 8;
    u16* bs1 = Bs + 32 * 64 + t * 8;

    for (int k0 = 0; k0 < DD; k0 += 64) {
        __syncthreads();
#pragma unroll
        for (int u = 0; u < 4; u++) gld_lds16(agp[u] + k0, asp[u]);
        gld_lds16(bg0 + k0, bs0);
        gld_lds16(bg1 + k0, bs1);
        __syncthreads();
#pragma unroll
        for (int h = 0; h < 2; h++) {
            short8 af[4], bf[2];
#pragma unroll
            for (int i = 0; i < 4; i++) af[i] = *(const short8*)&As[(wm + 16 * i + fr) * 64 + h * 32 + fq];
#pragma unroll
            for (int j = 0; j < 2; j++) bf[j] = *(const short8*)&Bs[(wn + 16 * j + fr) * 64 + h * 32 + fq];
#pragma unroll
            for (int i = 0; i < 4; i++)
#pragma unroll
                for (int j = 0; j < 2; j++)
                    acc[i][j] = __builtin_amdgcn_mfma_f32_16x16x32_bf16(af[i], bf[j], acc[i][j], 0, 0, 0);
        }
    }

    const int er = (lane >> 4) * 4, ec = lane & 15;
#pragma unroll
    for (int j = 0; j < 2; j++) {
        int col = n0 + wn + 16 * j + ec;
        float bsv = bias[col];
#pragma unroll
        for (int i = 0; i < 4; i++) {
#pragma unroll
            for (int r = 0; r < 4; r++) {
                int row = m0 + wm + 16 * i + er + r;
                outB[(size_t)row * 1536 + col] = f2bf(acc[i][j][r] + bsv);
            }
        }
    }
}

// ---------------------------------------------------------------- sparse attention (R7-proven)
__global__ void sparse_attn(const u16* __restrict__ qkv, const int* __restrict__ idx,
                            const int* __restrict__ cnt, u16* __restrict__ o) {
    int t = threadIdx.x;
    int wave = t >> 6, lane = t & 63;
    int qslot = wave >> 1, half = wave & 1;
    int qi = blockIdx.x * 4 + qslot;
    __shared__ float obuf[4][64][8];
    __shared__ float sbuf[4][64];
    __shared__ int sidx[4][CAP];

    int c = cnt[qi];
    const int* ir = idx + qi * CAP;
    for (int j = t & 127; j < c; j += 128) sidx[qslot][j] = ir[j];

    ushort8 qv = *(const ushort8*)(qkv + (size_t)qi * 1536 + lane * 8);
    float qf[8];
#pragma unroll
    for (int e = 0; e < 8; e++) qf[e] = bf2f(qv[e]);
    __syncthreads();

    float sum = 0.f, oa[8] = {};
    int j = half;
    ushort8 kv, vv;
    if (j < c) {
        const u16* kb = qkv + (size_t)sidx[qslot][j] * 1536;
        kv = *(const ushort8*)(kb + 512 + lane * 8);
        vv = *(const ushort8*)(kb + 1024 + lane * 8);
    }
    while (j < c) {
        int jn = j + 2;
        ushort8 kvn, vvn;
        {
            int kjn = (jn < c) ? sidx[qslot][jn] : 0;
            const u16* nb = qkv + (size_t)kjn * 1536;
            kvn = *(const ushort8*)(nb + 512 + lane * 8);
            vvn = *(const ushort8*)(nb + 1024 + lane * 8);
        }
        float d = 0.f;
#pragma unroll
        for (int e = 0; e < 8; e++) d += qf[e] * bf2f(kv[e]);
        d += __shfl_xor(d, 1);
        d += __shfl_xor(d, 2);
        d += __shfl_xor(d, 4);
        d += __shfl_xor(d, 8);
        float p = __expf(d * SCALE);
        sum += p;
#pragma unroll
        for (int e = 0; e < 8; e++) oa[e] += p * bf2f(vv[e]);
        kv = kvn; vv = vvn;
        j = jn;
    }

    if (half == 1) {
#pragma unroll
        for (int e = 0; e < 8; e++) obuf[qslot][lane][e] = oa[e];
        sbuf[qslot][lane] = sum;
    }
    __syncthreads();
    if (half == 0) {
        sum += sbuf[qslot][lane];
        float inv = 1.0f / sum;
        ushort8 ov;
#pragma unroll
        for (int e = 0; e < 8; e++) ov[e] = f2bf((oa[e] + obuf[qslot][lane][e]) * inv);
        *(ushort8*)(o + (size_t)qi * 512 + lane * 8) = ov;
    }
}

// ---------------------------------------------------------------- launch
extern "C" void kernel_launch(void* const* d_in, const int* in_sizes, int n_in,
                              void* d_out, int out_size, void* d_ws, size_t ws_size,
                              hipStream_t stream) {
    const float* nfeat = (const float*)d_in[0];
    const int*   mask  = (const int*)d_in[1];
    const float* ln1_g = (const float*)d_in[2];
    const float* ln1_b = (const float*)d_in[3];
    const float* bo    = (const float*)d_in[11];
    const float* ln2_g = (const float*)d_in[12];
    const float* ln2_b = (const float*)d_in[13];
    const float* fc1_b = (const float*)d_in[15];
    const float* fc2_b = (const float*)d_in[17];

    const size_t ND = (size_t)NN * DD;
    float* x    = (float*)d_ws;                      // 8 MB
    u16*   h    = (u16*)(x + ND);                    // 4 MB
    u16*   qkv  = h + ND;                            // 12 MB
    u16*   o    = qkv + (size_t)NN * 1536;           // 4 MB
    u16*   m1   = o + ND;                            // 4 MB
    u16*   wc   = m1 + ND;                           // 12 MB
    float* bcat = (float*)(wc + (size_t)12 * DD * DD);
    int*   idx  = (int*)(bcat + 2 * 1536);           // 4 MB
    int*   cnt  = idx + (size_t)NN * CAP;

    SetupArgs sa;
    sa.w[0] = (const float*)d_in[4];  sa.w[1] = (const float*)d_in[6];
    sa.w[2] = (const float*)d_in[8];  sa.w[3] = (const float*)d_in[10];
    sa.w[4] = (const float*)d_in[14]; sa.w[5] = (const float*)d_in[16];
    sa.bq = (const float*)d_in[5]; sa.bk = (const float*)d_in[7]; sa.bv = (const float*)d_in[9];
    sa.mask = mask; sa.wc = wc; sa.bcat = bcat; sa.idx = idx; sa.cnt = cnt;
    setup_kernel<<<192 + NN, 256, 0, stream>>>(sa);

    const size_t SS = (size_t)DD * DD;
    for (int l = 0; l < 2; l++) {
        size_t bOff = (size_t)l * DD;
        u16* wl = wc + (size_t)l * 6 * SS;
        const float* xin = (l == 0) ? nfeat : x;
        float* fc2_dst = (l == 1) ? (float*)d_out : x;

        ln_kernel<<<NN / 4, 256, 0, stream>>>(xin, ln1_g + bOff, ln1_b + bOff, h);
        gemm_qkv<<<dim3(24, 32), 256, 0, stream>>>(h, wl, bcat + l * 1536, qkv);
        sparse_attn<<<NN / 4, 512, 0, stream>>>(qkv, idx, cnt, o);
        gemm_bf16<2><<<dim3(8, 64), 256, 0, stream>>>(o, wl + 3 * SS, bo + bOff,
                                                      xin, x, nullptr, NN, DD, DD);
        ln_kernel<<<NN / 4, 256, 0, stream>>>(x, ln2_g + bOff, ln2_b + bOff, h);
        gemm_bf16<1><<<dim3(8, 64), 256, 0, stream>>>(h, wl + 4 * SS, fc1_b + bOff,
                                                      nullptr, nullptr, m1, NN, FF, DD);
        gemm_bf16<2><<<dim3(8, 64), 256, 0, stream>>>(m1, wl + 5 * SS, fc2_b + bOff,
                                                      x, fc2_dst, nullptr, NN, DD, FF);
    }
}

// Round 12
// 283.736 us; speedup vs baseline: 1.0491x; 1.0491x over previous
//
#include <hip/hip_runtime.h>
#include <math.h>

#define NN 4096
#define DD 512
#define FF 512
#define CAP 256
#define SCALE 0.08838834764831845f

typedef unsigned short u16;
typedef __attribute__((ext_vector_type(8))) short short8;
typedef __attribute__((ext_vector_type(8))) unsigned short ushort8;
typedef __attribute__((ext_vector_type(4))) unsigned short ushort4v;
typedef __attribute__((ext_vector_type(4))) float floatx4;

__device__ __forceinline__ float bf2f(u16 u) {
    union { unsigned int i; float f; } x; x.i = ((unsigned int)u) << 16; return x.f;
}
__device__ __forceinline__ u16 f2bf(float f) {
    union { float f; unsigned int i; } x; x.f = f;
    unsigned int r = (x.i + 0x7FFFu + ((x.i >> 16) & 1u)) >> 16;
    return (u16)r;
}
__device__ __forceinline__ void gld_lds16(const void* g, void* l) {
    __builtin_amdgcn_global_load_lds((const __attribute__((address_space(1))) void*)g,
                                     (__attribute__((address_space(3))) void*)l, 16, 0, 0);
}

// ---------------------------------------------------------------- mask -> idx (R3-proven)
__global__ void build_idx_kernel(const int* __restrict__ mask,
                                 int* __restrict__ idx, int* __restrict__ cnt) {
    int row = blockIdx.x;
    __shared__ int c;
    if (threadIdx.x == 0) c = 0;
    __syncthreads();
    const int4* mrow = (const int4*)(mask + (size_t)row * NN);
    for (int j4 = threadIdx.x; j4 < NN / 4; j4 += blockDim.x) {
        int4 m4 = mrow[j4];
        int base = j4 * 4;
        if (m4.x == 0) idx[row * CAP + atomicAdd(&c, 1)] = base;
        if (m4.y == 0) idx[row * CAP + atomicAdd(&c, 1)] = base + 1;
        if (m4.z == 0) idx[row * CAP + atomicAdd(&c, 1)] = base + 2;
        if (m4.w == 0) idx[row * CAP + atomicAdd(&c, 1)] = base + 3;
    }
    __syncthreads();
    if (threadIdx.x == 0) cnt[row] = (c < CAP) ? c : CAP;
}

// ---------------------------------------------------------------- weights fp32 -> bf16 (+ bias concat)
struct W6 {
    const float* w[6];
    const float* bq; const float* bk; const float* bv;
};
__global__ void cast_weights(W6 wp, u16* __restrict__ dst, float* __restrict__ bcat) {
    int region = blockIdx.x >> 4;
    int layer = region / 6, mat = region - layer * 6;
    const float* src = wp.w[mat] + (size_t)layer * (DD * DD);
    u16* d = dst + (size_t)region * (DD * DD);
    int off = (blockIdx.x & 15) * 16384 + threadIdx.x * 4;
#pragma unroll
    for (int i = 0; i < 16; i++) {
        int e = off + i * 1024;
        float4 f = *(const float4*)&src[e];
        ushort4v u;
        u.x = f2bf(f.x); u.y = f2bf(f.y); u.z = f2bf(f.z); u.w = f2bf(f.w);
        *(ushort4v*)&d[e] = u;
    }
    if (blockIdx.x < 2) {   // bias concat for layer = blockIdx.x
        int l = blockIdx.x;
        for (int it = 0; it < 6; it++) {
            int j = it * 256 + threadIdx.x;          // 0..1535
            int m = j >> 9, col = j & 511;
            const float* bp = (m == 0) ? wp.bq : (m == 1) ? wp.bk : wp.bv;
            bcat[l * 1536 + j] = bp[l * DD + col];
        }
    }
}

// ---------------------------------------------------------------- layernorm (fp32 in, bf16 out)
__global__ void ln_kernel(const float* __restrict__ x, const float* __restrict__ g,
                          const float* __restrict__ b, u16* __restrict__ out) {
    int wave = threadIdx.x >> 6, lane = threadIdx.x & 63;
    int row = blockIdx.x * 4 + wave;
    const float* xr = x + (size_t)row * DD;
    float4 p0 = *(const float4*)&xr[lane * 8];
    float4 p1 = *(const float4*)&xr[lane * 8 + 4];
    float v[8] = {p0.x, p0.y, p0.z, p0.w, p1.x, p1.y, p1.z, p1.w};
    float s = 0.f;
#pragma unroll
    for (int i = 0; i < 8; i++) s += v[i];
#pragma unroll
    for (int off = 32; off; off >>= 1) s += __shfl_xor(s, off);
    float mu = s * (1.0f / DD);
    float vs = 0.f;
#pragma unroll
    for (int i = 0; i < 8; i++) { float d = v[i] - mu; vs += d * d; }
#pragma unroll
    for (int off = 32; off; off >>= 1) vs += __shfl_xor(vs, off);
    float r = rsqrtf(vs * (1.0f / DD) + 1e-5f);
    float4 g0 = *(const float4*)&g[lane * 8];
    float4 g1 = *(const float4*)&g[lane * 8 + 4];
    float4 b0 = *(const float4*)&b[lane * 8];
    float4 b1 = *(const float4*)&b[lane * 8 + 4];
    float ge[8] = {g0.x, g0.y, g0.z, g0.w, g1.x, g1.y, g1.z, g1.w};
    float be[8] = {b0.x, b0.y, b0.z, b0.w, b1.x, b1.y, b1.z, b1.w};
    ushort8 ov;
#pragma unroll
    for (int i = 0; i < 8; i++) ov[i] = f2bf((v[i] - mu) * r * ge[i] + be[i]);
    *(ushort8*)&out[(size_t)row * DD + lane * 8] = ov;
}

// LDS row-rotation swizzle (BK=64, 8 chunks of 16B per row):
//   LDS(row, pos) holds global chunk (pos - row) & 7.
//   Stager thread t (row t>>3, LDS pos t&7) fetches global chunk ((t&7)-(t>>3))&7;
//   LDS dest stays base + t*8 (wave-uniform + lane*16 -> global_load_lds legal).
//   Reader of global chunk g at row R uses pos (g + R) & 7; all row-block offsets
//   are 0 mod 8, so pos = (g + fr) & 7. 16-lane groups spread over all 32 banks
//   (8 dwords/bank uniform) vs unswizzled 16 banks x 16 (2x serialization).

// ---------------------------------------------------------------- 64x64 GEMM, BK=64, swizzled
// MODE 0: -> bf16; 1: gelu -> bf16; 2: resOut = resIn + val (fp32)
template <int MODE>
__launch_bounds__(256)
__global__ void gemm_bf16(const u16* __restrict__ A, const u16* __restrict__ B,
                          const float* __restrict__ bias, const float* __restrict__ resIn,
                          float* __restrict__ resOut, u16* __restrict__ outB,
                          int M, int Nout, int K) {
    __shared__ u16 As[64 * 64];
    __shared__ u16 Bs[64 * 64];
    const int m0 = blockIdx.y * 64, n0 = blockIdx.x * 64;
    const int t = threadIdx.x;
    const int wave = t >> 6, lane = t & 63;
    const int wm = (wave & 1) * 32, wn = (wave >> 1) * 32;
    const int sr = t >> 3;
    const int sc = ((((t & 7) - (t >> 3)) & 7)) * 8;    // swizzled global chunk
    const int fr = lane & 15, g0 = lane >> 4;

    floatx4 acc[2][2] = {};
    const u16* ag0 = A + (size_t)(m0 + sr) * K + sc;
    const u16* ag1 = A + (size_t)(m0 + 32 + sr) * K + sc;
    const u16* bg0 = B + (size_t)(n0 + sr) * K + sc;
    const u16* bg1 = B + (size_t)(n0 + 32 + sr) * K + sc;
    u16* as0 = As + t * 8;
    u16* as1 = As + 32 * 64 + t * 8;
    u16* bs0 = Bs + t * 8;
    u16* bs1 = Bs + 32 * 64 + t * 8;

    for (int k0 = 0; k0 < K; k0 += 64) {
        __syncthreads();
        gld_lds16(ag0 + k0, as0);
        gld_lds16(ag1 + k0, as1);
        gld_lds16(bg0 + k0, bs0);
        gld_lds16(bg1 + k0, bs1);
        __syncthreads();
#pragma unroll
        for (int h = 0; h < 2; h++) {
            const int fo = (((h << 2) + g0 + fr) & 7) << 3;   // swizzled read offset
            short8 af[2], bf[2];
#pragma unroll
            for (int i = 0; i < 2; i++) af[i] = *(const short8*)&As[(wm + 16 * i + fr) * 64 + fo];
#pragma unroll
            for (int j = 0; j < 2; j++) bf[j] = *(const short8*)&Bs[(wn + 16 * j + fr) * 64 + fo];
#pragma unroll
            for (int i = 0; i < 2; i++)
#pragma unroll
                for (int j = 0; j < 2; j++)
                    acc[i][j] = __builtin_amdgcn_mfma_f32_16x16x32_bf16(af[i], bf[j], acc[i][j], 0, 0, 0);
        }
    }

    const int er = (lane >> 4) * 4, ec = lane & 15;
#pragma unroll
    for (int i = 0; i < 2; i++) {
#pragma unroll
        for (int j = 0; j < 2; j++) {
            int col = n0 + wn + 16 * j + ec;
            float bsv = bias[col];
#pragma unroll
            for (int r = 0; r < 4; r++) {
                int row = m0 + wm + 16 * i + er + r;
                float val = acc[i][j][r] + bsv;
                if (MODE == 1) val = 0.5f * val * (1.0f + erff(val * 0.70710678118654752f));
                if (MODE == 2) {
                    resOut[(size_t)row * Nout + col] = resIn[(size_t)row * Nout + col] + val;
                } else {
                    outB[(size_t)row * Nout + col] = f2bf(val);
                }
            }
        }
    }
}

// ---------------------------------------------------------------- 128x64 QKV GEMM, BK=64, swizzled
__launch_bounds__(256)
__global__ void gemm_qkv(const u16* __restrict__ A, const u16* __restrict__ B,
                         const float* __restrict__ bias, u16* __restrict__ outB) {
    __shared__ u16 As[128 * 64];   // 16 KB
    __shared__ u16 Bs[64 * 64];    // 8 KB
    const int m0 = blockIdx.y * 128, n0 = blockIdx.x * 64;
    const int t = threadIdx.x;
    const int wave = t >> 6, lane = t & 63;
    const int wm = (wave & 1) * 64, wn = (wave >> 1) * 32;
    const int sr = t >> 3;
    const int sc = ((((t & 7) - (t >> 3)) & 7)) * 8;
    const int fr = lane & 15, g0 = lane >> 4;

    floatx4 acc[4][2] = {};
    const u16* agp[4];
    u16* asp[4];
#pragma unroll
    for (int u = 0; u < 4; u++) {
        agp[u] = A + (size_t)(m0 + 32 * u + sr) * DD + sc;
        asp[u] = As + u * (32 * 64) + t * 8;
    }
    const u16* bg0 = B + (size_t)(n0 + sr) * DD + sc;
    const u16* bg1 = B + (size_t)(n0 + 32 + sr) * DD + sc;
    u16* bs0 = Bs + t * 8;
    u16* bs1 = Bs + 32 * 64 + t * 8;

    for (int k0 = 0; k0 < DD; k0 += 64) {
        __syncthreads();
#pragma unroll
        for (int u = 0; u < 4; u++) gld_lds16(agp[u] + k0, asp[u]);
        gld_lds16(bg0 + k0, bs0);
        gld_lds16(bg1 + k0, bs1);
        __syncthreads();
#pragma unroll
        for (int h = 0; h < 2; h++) {
            const int fo = (((h << 2) + g0 + fr) & 7) << 3;
            short8 af[4], bf[2];
#pragma unroll
            for (int i = 0; i < 4; i++) af[i] = *(const short8*)&As[(wm + 16 * i + fr) * 64 + fo];
#pragma unroll
            for (int j = 0; j < 2; j++) bf[j] = *(const short8*)&Bs[(wn + 16 * j + fr) * 64 + fo];
#pragma unroll
            for (int i = 0; i < 4; i++)
#pragma unroll
                for (int j = 0; j < 2; j++)
                    acc[i][j] = __builtin_amdgcn_mfma_f32_16x16x32_bf16(af[i], bf[j], acc[i][j], 0, 0, 0);
        }
    }

    const int er = (lane >> 4) * 4, ec = lane & 15;
#pragma unroll
    for (int j = 0; j < 2; j++) {
        int col = n0 + wn + 16 * j + ec;
        float bsv = bias[col];
#pragma unroll
        for (int i = 0; i < 4; i++) {
#pragma unroll
            for (int r = 0; r < 4; r++) {
                int row = m0 + wm + 16 * i + er + r;
                outB[(size_t)row * 1536 + col] = f2bf(acc[i][j][r] + bsv);
            }
        }
    }
}

// ---------------------------------------------------------------- sparse attention (R7-proven)
__global__ void sparse_attn(const u16* __restrict__ qkv, const int* __restrict__ idx,
                            const int* __restrict__ cnt, u16* __restrict__ o) {
    int t = threadIdx.x;
    int wave = t >> 6, lane = t & 63;
    int qslot = wave >> 1, half = wave & 1;
    int qi = blockIdx.x * 4 + qslot;
    __shared__ float obuf[4][64][8];
    __shared__ float sbuf[4][64];
    __shared__ int sidx[4][CAP];

    int c = cnt[qi];
    const int* ir = idx + qi * CAP;
    for (int j = t & 127; j < c; j += 128) sidx[qslot][j] = ir[j];

    ushort8 qv = *(const ushort8*)(qkv + (size_t)qi * 1536 + lane * 8);
    float qf[8];
#pragma unroll
    for (int e = 0; e < 8; e++) qf[e] = bf2f(qv[e]);
    __syncthreads();

    float sum = 0.f, oa[8] = {};
    int j = half;
    ushort8 kv, vv;
    if (j < c) {
        const u16* kb = qkv + (size_t)sidx[qslot][j] * 1536;
        kv = *(const ushort8*)(kb + 512 + lane * 8);
        vv = *(const ushort8*)(kb + 1024 + lane * 8);
    }
    while (j < c) {
        int jn = j + 2;
        ushort8 kvn, vvn;
        {
            int kjn = (jn < c) ? sidx[qslot][jn] : 0;
            const u16* nb = qkv + (size_t)kjn * 1536;
            kvn = *(const ushort8*)(nb + 512 + lane * 8);
            vvn = *(const ushort8*)(nb + 1024 + lane * 8);
        }
        float d = 0.f;
#pragma unroll
        for (int e = 0; e < 8; e++) d += qf[e] * bf2f(kv[e]);
        d += __shfl_xor(d, 1);
        d += __shfl_xor(d, 2);
        d += __shfl_xor(d, 4);
        d += __shfl_xor(d, 8);
        float p = __expf(d * SCALE);
        sum += p;
#pragma unroll
        for (int e = 0; e < 8; e++) oa[e] += p * bf2f(vv[e]);
        kv = kvn; vv = vvn;
        j = jn;
    }

    if (half == 1) {
#pragma unroll
        for (int e = 0; e < 8; e++) obuf[qslot][lane][e] = oa[e];
        sbuf[qslot][lane] = sum;
    }
    __syncthreads();
    if (half == 0) {
        sum += sbuf[qslot][lane];
        float inv = 1.0f / sum;
        ushort8 ov;
#pragma unroll
        for (int e = 0; e < 8; e++) ov[e] = f2bf((oa[e] + obuf[qslot][lane][e]) * inv);
        *(ushort8*)(o + (size_t)qi * 512 + lane * 8) = ov;
    }
}

// ---------------------------------------------------------------- launch
extern "C" void kernel_launch(void* const* d_in, const int* in_sizes, int n_in,
                              void* d_out, int out_size, void* d_ws, size_t ws_size,
                              hipStream_t stream) {
    const float* nfeat = (const float*)d_in[0];
    const int*   mask  = (const int*)d_in[1];
    const float* ln1_g = (const float*)d_in[2];
    const float* ln1_b = (const float*)d_in[3];
    const float* bo    = (const float*)d_in[11];
    const float* ln2_g = (const float*)d_in[12];
    const float* ln2_b = (const float*)d_in[13];
    const float* fc1_b = (const float*)d_in[15];
    const float* fc2_b = (const float*)d_in[17];

    const size_t ND = (size_t)NN * DD;
    float* x    = (float*)d_ws;                      // 8 MB
    u16*   h    = (u16*)(x + ND);                    // 4 MB
    u16*   qkv  = h + ND;                            // 12 MB
    u16*   o    = qkv + (size_t)NN * 1536;           // 4 MB
    u16*   m1   = o + ND;                            // 4 MB
    u16*   wc   = m1 + ND;                           // 12 MB
    float* bcat = (float*)(wc + (size_t)12 * DD * DD);
    int*   idx  = (int*)(bcat + 2 * 1536);           // 4 MB
    int*   cnt  = idx + (size_t)NN * CAP;

    W6 w6;
    w6.w[0] = (const float*)d_in[4];  w6.w[1] = (const float*)d_in[6];
    w6.w[2] = (const float*)d_in[8];  w6.w[3] = (const float*)d_in[10];
    w6.w[4] = (const float*)d_in[14]; w6.w[5] = (const float*)d_in[16];
    w6.bq = (const float*)d_in[5]; w6.bk = (const float*)d_in[7]; w6.bv = (const float*)d_in[9];
    cast_weights<<<192, 256, 0, stream>>>(w6, wc, bcat);
    build_idx_kernel<<<NN, 256, 0, stream>>>(mask, idx, cnt);

    const size_t SS = (size_t)DD * DD;
    for (int l = 0; l < 2; l++) {
        size_t bOff = (size_t)l * DD;
        u16* wl = wc + (size_t)l * 6 * SS;
        const float* xin = (l == 0) ? nfeat : x;
        float* fc2_dst = (l == 1) ? (float*)d_out : x;

        ln_kernel<<<NN / 4, 256, 0, stream>>>(xin, ln1_g + bOff, ln1_b + bOff, h);
        gemm_qkv<<<dim3(24, 32), 256, 0, stream>>>(h, wl, bcat + l * 1536, qkv);
        sparse_attn<<<NN / 4, 512, 0, stream>>>(qkv, idx, cnt, o);
        gemm_bf16<2><<<dim3(8, 64), 256, 0, stream>>>(o, wl + 3 * SS, bo + bOff,
                                                      xin, x, nullptr, NN, DD, DD);
        ln_kernel<<<NN / 4, 256, 0, stream>>>(x, ln2_g + bOff, ln2_b + bOff, h);
        gemm_bf16<1><<<dim3(8, 64), 256, 0, stream>>>(h, wl + 4 * SS, fc1_b + bOff,
                                                      nullptr, nullptr, m1, NN, FF, DD);
        gemm_bf16<2><<<dim3(8, 64), 256, 0, stream>>>(m1, wl + 5 * SS, fc2_b + bOff,
                                                      x, fc2_dst, nullptr, NN, DD, FF);
    }
}

// Round 13
// 278.945 us; speedup vs baseline: 1.0671x; 1.0172x over previous
//
#include <hip/hip_runtime.h>
#include <math.h>

#define NN 4096
#define DD 512
#define FF 512
#define CAP 256
#define SCALE 0.08838834764831845f

typedef unsigned short u16;
typedef __attribute__((ext_vector_type(8))) short short8;
typedef __attribute__((ext_vector_type(8))) unsigned short ushort8;
typedef __attribute__((ext_vector_type(4))) unsigned short ushort4v;
typedef __attribute__((ext_vector_type(4))) float floatx4;
typedef _Float16 half8v __attribute__((ext_vector_type(8)));
typedef _Float16 h2v __attribute__((ext_vector_type(2)));

__device__ __forceinline__ float bf2f(u16 u) {
    union { unsigned int i; float f; } x; x.i = ((unsigned int)u) << 16; return x.f;
}
__device__ __forceinline__ u16 f2bf(float f) {
    union { float f; unsigned int i; } x; x.f = f;
    unsigned int r = (x.i + 0x7FFFu + ((x.i >> 16) & 1u)) >> 16;
    return (u16)r;
}
__device__ __forceinline__ u16 f2h(float f) {
    _Float16 h = (_Float16)f;
    union { _Float16 h; u16 u; } x; x.h = h; return x.u;
}
__device__ __forceinline__ void gld_lds16(const void* g, void* l) {
    __builtin_amdgcn_global_load_lds((const __attribute__((address_space(1))) void*)g,
                                     (__attribute__((address_space(3))) void*)l, 16, 0, 0);
}

// ---------------------------------------------------------------- mask -> idx (R3-proven)
__global__ void build_idx_kernel(const int* __restrict__ mask,
                                 int* __restrict__ idx, int* __restrict__ cnt) {
    int row = blockIdx.x;
    __shared__ int c;
    if (threadIdx.x == 0) c = 0;
    __syncthreads();
    const int4* mrow = (const int4*)(mask + (size_t)row * NN);
    for (int j4 = threadIdx.x; j4 < NN / 4; j4 += blockDim.x) {
        int4 m4 = mrow[j4];
        int base = j4 * 4;
        if (m4.x == 0) idx[row * CAP + atomicAdd(&c, 1)] = base;
        if (m4.y == 0) idx[row * CAP + atomicAdd(&c, 1)] = base + 1;
        if (m4.z == 0) idx[row * CAP + atomicAdd(&c, 1)] = base + 2;
        if (m4.w == 0) idx[row * CAP + atomicAdd(&c, 1)] = base + 3;
    }
    __syncthreads();
    if (threadIdx.x == 0) cnt[row] = (c < CAP) ? c : CAP;
}

// ---------------------------------------------------------------- weights fp32 -> bf16 (+ bias concat)
struct W6 {
    const float* w[6];
    const float* bq; const float* bk; const float* bv;
};
__global__ void cast_weights(W6 wp, u16* __restrict__ dst, float* __restrict__ bcat) {
    int region = blockIdx.x >> 4;
    int layer = region / 6, mat = region - layer * 6;
    const float* src = wp.w[mat] + (size_t)layer * (DD * DD);
    u16* d = dst + (size_t)region * (DD * DD);
    int off = (blockIdx.x & 15) * 16384 + threadIdx.x * 4;
#pragma unroll
    for (int i = 0; i < 16; i++) {
        int e = off + i * 1024;
        float4 f = *(const float4*)&src[e];
        ushort4v u;
        u.x = f2bf(f.x); u.y = f2bf(f.y); u.z = f2bf(f.z); u.w = f2bf(f.w);
        *(ushort4v*)&d[e] = u;
    }
    if (blockIdx.x < 2) {   // bias concat for layer = blockIdx.x
        int l = blockIdx.x;
        for (int it = 0; it < 6; it++) {
            int j = it * 256 + threadIdx.x;          // 0..1535
            int m = j >> 9, col = j & 511;
            const float* bp = (m == 0) ? wp.bq : (m == 1) ? wp.bk : wp.bv;
            bcat[l * 1536 + j] = bp[l * DD + col];
        }
    }
}

// ---------------------------------------------------------------- layernorm (fp32 in, bf16 out)
__global__ void ln_kernel(const float* __restrict__ x, const float* __restrict__ g,
                          const float* __restrict__ b, u16* __restrict__ out) {
    int wave = threadIdx.x >> 6, lane = threadIdx.x & 63;
    int row = blockIdx.x * 4 + wave;
    const float* xr = x + (size_t)row * DD;
    float4 p0 = *(const float4*)&xr[lane * 8];
    float4 p1 = *(const float4*)&xr[lane * 8 + 4];
    float v[8] = {p0.x, p0.y, p0.z, p0.w, p1.x, p1.y, p1.z, p1.w};
    float s = 0.f;
#pragma unroll
    for (int i = 0; i < 8; i++) s += v[i];
#pragma unroll
    for (int off = 32; off; off >>= 1) s += __shfl_xor(s, off);
    float mu = s * (1.0f / DD);
    float vs = 0.f;
#pragma unroll
    for (int i = 0; i < 8; i++) { float d = v[i] - mu; vs += d * d; }
#pragma unroll
    for (int off = 32; off; off >>= 1) vs += __shfl_xor(vs, off);
    float r = rsqrtf(vs * (1.0f / DD) + 1e-5f);
    float4 g0 = *(const float4*)&g[lane * 8];
    float4 g1 = *(const float4*)&g[lane * 8 + 4];
    float4 b0 = *(const float4*)&b[lane * 8];
    float4 b1 = *(const float4*)&b[lane * 8 + 4];
    float ge[8] = {g0.x, g0.y, g0.z, g0.w, g1.x, g1.y, g1.z, g1.w};
    float be[8] = {b0.x, b0.y, b0.z, b0.w, b1.x, b1.y, b1.z, b1.w};
    ushort8 ov;
#pragma unroll
    for (int i = 0; i < 8; i++) ov[i] = f2bf((v[i] - mu) * r * ge[i] + be[i]);
    *(ushort8*)&out[(size_t)row * DD + lane * 8] = ov;
}

// LDS row-rotation swizzle (R12-proven): LDS(row, pos) holds global chunk (pos - row) & 7.

// ---------------------------------------------------------------- 64x64 GEMM, BK=64, swizzled (R12-proven)
// MODE 0: -> bf16; 1: gelu -> bf16; 2: resOut = resIn + val (fp32)
template <int MODE>
__launch_bounds__(256)
__global__ void gemm_bf16(const u16* __restrict__ A, const u16* __restrict__ B,
                          const float* __restrict__ bias, const float* __restrict__ resIn,
                          float* __restrict__ resOut, u16* __restrict__ outB,
                          int M, int Nout, int K) {
    __shared__ u16 As[64 * 64];
    __shared__ u16 Bs[64 * 64];
    const int m0 = blockIdx.y * 64, n0 = blockIdx.x * 64;
    const int t = threadIdx.x;
    const int wave = t >> 6, lane = t & 63;
    const int wm = (wave & 1) * 32, wn = (wave >> 1) * 32;
    const int sr = t >> 3;
    const int sc = ((((t & 7) - (t >> 3)) & 7)) * 8;    // swizzled global chunk
    const int fr = lane & 15, g0 = lane >> 4;

    floatx4 acc[2][2] = {};
    const u16* ag0 = A + (size_t)(m0 + sr) * K + sc;
    const u16* ag1 = A + (size_t)(m0 + 32 + sr) * K + sc;
    const u16* bg0 = B + (size_t)(n0 + sr) * K + sc;
    const u16* bg1 = B + (size_t)(n0 + 32 + sr) * K + sc;
    u16* as0 = As + t * 8;
    u16* as1 = As + 32 * 64 + t * 8;
    u16* bs0 = Bs + t * 8;
    u16* bs1 = Bs + 32 * 64 + t * 8;

    for (int k0 = 0; k0 < K; k0 += 64) {
        __syncthreads();
        gld_lds16(ag0 + k0, as0);
        gld_lds16(ag1 + k0, as1);
        gld_lds16(bg0 + k0, bs0);
        gld_lds16(bg1 + k0, bs1);
        __syncthreads();
#pragma unroll
        for (int h = 0; h < 2; h++) {
            const int fo = (((h << 2) + g0 + fr) & 7) << 3;   // swizzled read offset
            short8 af[2], bf[2];
#pragma unroll
            for (int i = 0; i < 2; i++) af[i] = *(const short8*)&As[(wm + 16 * i + fr) * 64 + fo];
#pragma unroll
            for (int j = 0; j < 2; j++) bf[j] = *(const short8*)&Bs[(wn + 16 * j + fr) * 64 + fo];
#pragma unroll
            for (int i = 0; i < 2; i++)
#pragma unroll
                for (int j = 0; j < 2; j++)
                    acc[i][j] = __builtin_amdgcn_mfma_f32_16x16x32_bf16(af[i], bf[j], acc[i][j], 0, 0, 0);
        }
    }

    const int er = (lane >> 4) * 4, ec = lane & 15;
#pragma unroll
    for (int i = 0; i < 2; i++) {
#pragma unroll
        for (int j = 0; j < 2; j++) {
            int col = n0 + wn + 16 * j + ec;
            float bsv = bias[col];
#pragma unroll
            for (int r = 0; r < 4; r++) {
                int row = m0 + wm + 16 * i + er + r;
                float val = acc[i][j][r] + bsv;
                if (MODE == 1) val = 0.5f * val * (1.0f + erff(val * 0.70710678118654752f));
                if (MODE == 2) {
                    resOut[(size_t)row * Nout + col] = resIn[(size_t)row * Nout + col] + val;
                } else {
                    outB[(size_t)row * Nout + col] = f2bf(val);
                }
            }
        }
    }
}

// ---------------------------------------------------------------- 128x64 QKV GEMM, BK=64, swizzled
// Output: f16 (feeds attention only)
__launch_bounds__(256)
__global__ void gemm_qkv(const u16* __restrict__ A, const u16* __restrict__ B,
                         const float* __restrict__ bias, u16* __restrict__ outB) {
    __shared__ u16 As[128 * 64];   // 16 KB
    __shared__ u16 Bs[64 * 64];    // 8 KB
    const int m0 = blockIdx.y * 128, n0 = blockIdx.x * 64;
    const int t = threadIdx.x;
    const int wave = t >> 6, lane = t & 63;
    const int wm = (wave & 1) * 64, wn = (wave >> 1) * 32;
    const int sr = t >> 3;
    const int sc = ((((t & 7) - (t >> 3)) & 7)) * 8;
    const int fr = lane & 15, g0 = lane >> 4;

    floatx4 acc[4][2] = {};
    const u16* agp[4];
    u16* asp[4];
#pragma unroll
    for (int u = 0; u < 4; u++) {
        agp[u] = A + (size_t)(m0 + 32 * u + sr) * DD + sc;
        asp[u] = As + u * (32 * 64) + t * 8;
    }
    const u16* bg0 = B + (size_t)(n0 + sr) * DD + sc;
    const u16* bg1 = B + (size_t)(n0 + 32 + sr) * DD + sc;
    u16* bs0 = Bs + t * 8;
    u16* bs1 = Bs + 32 * 64 + t * 8;

    for (int k0 = 0; k0 < DD; k0 += 64) {
        __syncthreads();
#pragma unroll
        for (int u = 0; u < 4; u++) gld_lds16(agp[u] + k0, asp[u]);
        gld_lds16(bg0 + k0, bs0);
        gld_lds16(bg1 + k0, bs1);
        __syncthreads();
#pragma unroll
        for (int h = 0; h < 2; h++) {
            const int fo = (((h << 2) + g0 + fr) & 7) << 3;
            short8 af[4], bf[2];
#pragma unroll
            for (int i = 0; i < 4; i++) af[i] = *(const short8*)&As[(wm + 16 * i + fr) * 64 + fo];
#pragma unroll
            for (int j = 0; j < 2; j++) bf[j] = *(const short8*)&Bs[(wn + 16 * j + fr) * 64 + fo];
#pragma unroll
            for (int i = 0; i < 4; i++)
#pragma unroll
                for (int j = 0; j < 2; j++)
                    acc[i][j] = __builtin_amdgcn_mfma_f32_16x16x32_bf16(af[i], bf[j], acc[i][j], 0, 0, 0);
        }
    }

    const int er = (lane >> 4) * 4, ec = lane & 15;
#pragma unroll
    for (int j = 0; j < 2; j++) {
        int col = n0 + wn + 16 * j + ec;
        float bsv = bias[col];
#pragma unroll
        for (int i = 0; i < 4; i++) {
#pragma unroll
            for (int r = 0; r < 4; r++) {
                int row = m0 + wm + 16 * i + er + r;
                outB[(size_t)row * 1536 + col] = f2h(acc[i][j][r] + bsv);
            }
        }
    }
}

// ---------------------------------------------------------------- sparse attention (f16 QKV, fdot2)
// 2 waves/query, 4 queries/block; idx list in LDS; 2-deep K/V load pipeline (R7-proven structure)
__global__ void sparse_attn(const u16* __restrict__ qkv, const int* __restrict__ idx,
                            const int* __restrict__ cnt, u16* __restrict__ o) {
    int t = threadIdx.x;
    int wave = t >> 6, lane = t & 63;
    int qslot = wave >> 1, half = wave & 1;
    int qi = blockIdx.x * 4 + qslot;
    __shared__ float obuf[4][64][8];
    __shared__ float sbuf[4][64];
    __shared__ int sidx[4][CAP];

    int c = cnt[qi];
    const int* ir = idx + qi * CAP;
    for (int j = t & 127; j < c; j += 128) sidx[qslot][j] = ir[j];

    half8v qv = *(const half8v*)(qkv + (size_t)qi * 1536 + lane * 8);
    h2v q0 = __builtin_shufflevector(qv, qv, 0, 1);
    h2v q1 = __builtin_shufflevector(qv, qv, 2, 3);
    h2v q2 = __builtin_shufflevector(qv, qv, 4, 5);
    h2v q3 = __builtin_shufflevector(qv, qv, 6, 7);
    __syncthreads();

    float sum = 0.f, oa[8] = {};
    int j = half;
    half8v kv, vv;
    if (j < c) {
        const u16* kb = qkv + (size_t)sidx[qslot][j] * 1536;
        kv = *(const half8v*)(kb + 512 + lane * 8);
        vv = *(const half8v*)(kb + 1024 + lane * 8);
    }
    while (j < c) {
        int jn = j + 2;
        half8v kvn, vvn;
        {
            int kjn = (jn < c) ? sidx[qslot][jn] : 0;
            const u16* nb = qkv + (size_t)kjn * 1536;
            kvn = *(const half8v*)(nb + 512 + lane * 8);
            vvn = *(const half8v*)(nb + 1024 + lane * 8);
        }
        float d = 0.f;
        d = __builtin_amdgcn_fdot2(q0, __builtin_shufflevector(kv, kv, 0, 1), d, false);
        d = __builtin_amdgcn_fdot2(q1, __builtin_shufflevector(kv, kv, 2, 3), d, false);
        d = __builtin_amdgcn_fdot2(q2, __builtin_shufflevector(kv, kv, 4, 5), d, false);
        d = __builtin_amdgcn_fdot2(q3, __builtin_shufflevector(kv, kv, 6, 7), d, false);
        d += __shfl_xor(d, 1);
        d += __shfl_xor(d, 2);
        d += __shfl_xor(d, 4);
        d += __shfl_xor(d, 8);
        float p = __expf(d * SCALE);
        sum += p;
#pragma unroll
        for (int e = 0; e < 8; e++) oa[e] += p * (float)vv[e];
        kv = kvn; vv = vvn;
        j = jn;
    }

    if (half == 1) {
#pragma unroll
        for (int e = 0; e < 8; e++) obuf[qslot][lane][e] = oa[e];
        sbuf[qslot][lane] = sum;
    }
    __syncthreads();
    if (half == 0) {
        sum += sbuf[qslot][lane];
        float inv = 1.0f / sum;
        ushort8 ov;
#pragma unroll
        for (int e = 0; e < 8; e++) ov[e] = f2bf((oa[e] + obuf[qslot][lane][e]) * inv);
        *(ushort8*)(o + (size_t)qi * 512 + lane * 8) = ov;
    }
}

// ---------------------------------------------------------------- launch
extern "C" void kernel_launch(void* const* d_in, const int* in_sizes, int n_in,
                              void* d_out, int out_size, void* d_ws, size_t ws_size,
                              hipStream_t stream) {
    const float* nfeat = (const float*)d_in[0];
    const int*   mask  = (const int*)d_in[1];
    const float* ln1_g = (const float*)d_in[2];
    const float* ln1_b = (const float*)d_in[3];
    const float* bo    = (const float*)d_in[11];
    const float* ln2_g = (const float*)d_in[12];
    const float* ln2_b = (const float*)d_in[13];
    const float* fc1_b = (const float*)d_in[15];
    const float* fc2_b = (const float*)d_in[17];

    const size_t ND = (size_t)NN * DD;
    float* x    = (float*)d_ws;                      // 8 MB
    u16*   h    = (u16*)(x + ND);                    // 4 MB
    u16*   qkv  = h + ND;                            // 12 MB
    u16*   o    = qkv + (size_t)NN * 1536;           // 4 MB
    u16*   m1   = o + ND;                            // 4 MB
    u16*   wc   = m1 + ND;                           // 12 MB
    float* bcat = (float*)(wc + (size_t)12 * DD * DD);
    int*   idx  = (int*)(bcat + 2 * 1536);           // 4 MB
    int*   cnt  = idx + (size_t)NN * CAP;

    W6 w6;
    w6.w[0] = (const float*)d_in[4];  w6.w[1] = (const float*)d_in[6];
    w6.w[2] = (const float*)d_in[8];  w6.w[3] = (const float*)d_in[10];
    w6.w[4] = (const float*)d_in[14]; w6.w[5] = (const float*)d_in[16];
    w6.bq = (const float*)d_in[5]; w6.bk = (const float*)d_in[7]; w6.bv = (const float*)d_in[9];
    cast_weights<<<192, 256, 0, stream>>>(w6, wc, bcat);
    build_idx_kernel<<<NN, 256, 0, stream>>>(mask, idx, cnt);

    const size_t SS = (size_t)DD * DD;
    for (int l = 0; l < 2; l++) {
        size_t bOff = (size_t)l * DD;
        u16* wl = wc + (size_t)l * 6 * SS;
        const float* xin = (l == 0) ? nfeat : x;
        float* fc2_dst = (l == 1) ? (float*)d_out : x;

        ln_kernel<<<NN / 4, 256, 0, stream>>>(xin, ln1_g + bOff, ln1_b + bOff, h);
        gemm_qkv<<<dim3(24, 32), 256, 0, stream>>>(h, wl, bcat + l * 1536, qkv);
        sparse_attn<<<NN / 4, 512, 0, stream>>>(qkv, idx, cnt, o);
        gemm_bf16<2><<<dim3(8, 64), 256, 0, stream>>>(o, wl + 3 * SS, bo + bOff,
                                                      xin, x, nullptr, NN, DD, DD);
        ln_kernel<<<NN / 4, 256, 0, stream>>>(x, ln2_g + bOff, ln2_b + bOff, h);
        gemm_bf16<1><<<dim3(8, 64), 256, 0, stream>>>(h, wl + 4 * SS, fc1_b + bOff,
                                                      nullptr, nullptr, m1, NN, FF, DD);
        gemm_bf16<2><<<dim3(8, 64), 256, 0, stream>>>(m1, wl + 5 * SS, fc2_b + bOff,
                                                      x, fc2_dst, nullptr, NN, DD, FF);
    }
}

// Round 14
// 273.416 us; speedup vs baseline: 1.0887x; 1.0202x over previous
//
#include <hip/hip_runtime.h>
#include <math.h>

#define NN 4096
#define DD 512
#define FF 512
#define CAP 256
#define SCALE 0.08838834764831845f

typedef unsigned short u16;
typedef unsigned char u8;
typedef __attribute__((ext_vector_type(8))) short short8;
typedef __attribute__((ext_vector_type(8))) unsigned short ushort8;
typedef __attribute__((ext_vector_type(4))) unsigned short ushort4v;
typedef __attribute__((ext_vector_type(4))) float floatx4;
typedef __attribute__((ext_vector_type(2))) float f32x2;
typedef _Float16 half8v __attribute__((ext_vector_type(8)));

__device__ __forceinline__ float bf2f(u16 u) {
    union { unsigned int i; float f; } x; x.i = ((unsigned int)u) << 16; return x.f;
}
__device__ __forceinline__ u16 f2bf(float f) {
    union { float f; unsigned int i; } x; x.f = f;
    unsigned int r = (x.i + 0x7FFFu + ((x.i >> 16) & 1u)) >> 16;
    return (u16)r;
}
__device__ __forceinline__ u16 f2h(float f) {
    _Float16 h = (_Float16)f;
    union { _Float16 h; u16 u; } x; x.h = h; return x.u;
}
// f32 -> fp8 e4m3 (RNE) via the f16 domain: e4m3 bits == f16 bits of (x/256) >> 7.
// Valid for |x| <= 8 (no saturation / inf cases here).
__device__ __forceinline__ u8 f2fp8(float f) {
    union { _Float16 h; u16 u; } x;
    x.h = (_Float16)(f * 0.00390625f);          // /256
    u16 h = x.u;
    h = h + 0x3F + ((h >> 7) & 1);              // RNE on the 7 dropped bits
    return (u8)(((h >> 8) & 0x80) | ((h >> 7) & 0x7f));
}
__device__ __forceinline__ float fp82f_sw(u8 b) {   // exact software decode
    union { u16 u; _Float16 h; } x;
    x.u = (u16)(((u16)(b & 0x80) << 8) | ((u16)(b & 0x7f) << 7));
    return (float)x.h * 256.0f;
}
__device__ __forceinline__ void gld_lds16(const void* g, void* l) {
    __builtin_amdgcn_global_load_lds((const __attribute__((address_space(1))) void*)g,
                                     (__attribute__((address_space(3))) void*)l, 16, 0, 0);
}

// ---------------------------------------------------------------- mask -> idx (R3-proven)
__global__ void build_idx_kernel(const int* __restrict__ mask,
                                 int* __restrict__ idx, int* __restrict__ cnt) {
    int row = blockIdx.x;
    __shared__ int c;
    if (threadIdx.x == 0) c = 0;
    __syncthreads();
    const int4* mrow = (const int4*)(mask + (size_t)row * NN);
    for (int j4 = threadIdx.x; j4 < NN / 4; j4 += blockDim.x) {
        int4 m4 = mrow[j4];
        int base = j4 * 4;
        if (m4.x == 0) idx[row * CAP + atomicAdd(&c, 1)] = base;
        if (m4.y == 0) idx[row * CAP + atomicAdd(&c, 1)] = base + 1;
        if (m4.z == 0) idx[row * CAP + atomicAdd(&c, 1)] = base + 2;
        if (m4.w == 0) idx[row * CAP + atomicAdd(&c, 1)] = base + 3;
    }
    __syncthreads();
    if (threadIdx.x == 0) cnt[row] = (c < CAP) ? c : CAP;
}

// ---------------------------------------------------------------- weights fp32 -> bf16 (+ bias concat)
struct W6 {
    const float* w[6];
    const float* bq; const float* bk; const float* bv;
};
__global__ void cast_weights(W6 wp, u16* __restrict__ dst, float* __restrict__ bcat) {
    int region = blockIdx.x >> 4;
    int layer = region / 6, mat = region - layer * 6;
    const float* src = wp.w[mat] + (size_t)layer * (DD * DD);
    u16* d = dst + (size_t)region * (DD * DD);
    int off = (blockIdx.x & 15) * 16384 + threadIdx.x * 4;
#pragma unroll
    for (int i = 0; i < 16; i++) {
        int e = off + i * 1024;
        float4 f = *(const float4*)&src[e];
        ushort4v u;
        u.x = f2bf(f.x); u.y = f2bf(f.y); u.z = f2bf(f.z); u.w = f2bf(f.w);
        *(ushort4v*)&d[e] = u;
    }
    if (blockIdx.x < 2) {   // bias concat for layer = blockIdx.x
        int l = blockIdx.x;
        for (int it = 0; it < 6; it++) {
            int j = it * 256 + threadIdx.x;          // 0..1535
            int m = j >> 9, col = j & 511;
            const float* bp = (m == 0) ? wp.bq : (m == 1) ? wp.bk : wp.bv;
            bcat[l * 1536 + j] = bp[l * DD + col];
        }
    }
}

// ---------------------------------------------------------------- layernorm (fp32 in, bf16 out)
__global__ void ln_kernel(const float* __restrict__ x, const float* __restrict__ g,
                          const float* __restrict__ b, u16* __restrict__ out) {
    int wave = threadIdx.x >> 6, lane = threadIdx.x & 63;
    int row = blockIdx.x * 4 + wave;
    const float* xr = x + (size_t)row * DD;
    float4 p0 = *(const float4*)&xr[lane * 8];
    float4 p1 = *(const float4*)&xr[lane * 8 + 4];
    float v[8] = {p0.x, p0.y, p0.z, p0.w, p1.x, p1.y, p1.z, p1.w};
    float s = 0.f;
#pragma unroll
    for (int i = 0; i < 8; i++) s += v[i];
#pragma unroll
    for (int off = 32; off; off >>= 1) s += __shfl_xor(s, off);
    float mu = s * (1.0f / DD);
    float vs = 0.f;
#pragma unroll
    for (int i = 0; i < 8; i++) { float d = v[i] - mu; vs += d * d; }
#pragma unroll
    for (int off = 32; off; off >>= 1) vs += __shfl_xor(vs, off);
    float r = rsqrtf(vs * (1.0f / DD) + 1e-5f);
    float4 g0 = *(const float4*)&g[lane * 8];
    float4 g1 = *(const float4*)&g[lane * 8 + 4];
    float4 b0 = *(const float4*)&b[lane * 8];
    float4 b1 = *(const float4*)&b[lane * 8 + 4];
    float ge[8] = {g0.x, g0.y, g0.z, g0.w, g1.x, g1.y, g1.z, g1.w};
    float be[8] = {b0.x, b0.y, b0.z, b0.w, b1.x, b1.y, b1.z, b1.w};
    ushort8 ov;
#pragma unroll
    for (int i = 0; i < 8; i++) ov[i] = f2bf((v[i] - mu) * r * ge[i] + be[i]);
    *(ushort8*)&out[(size_t)row * DD + lane * 8] = ov;
}

// LDS row-rotation swizzle (R12-proven): LDS(row, pos) holds global chunk (pos - row) & 7.

// ---------------------------------------------------------------- 64x64 GEMM, BK=64, swizzled (R12-proven)
// MODE 0: -> bf16; 1: gelu -> bf16; 2: resOut = resIn + val (fp32)
template <int MODE>
__launch_bounds__(256)
__global__ void gemm_bf16(const u16* __restrict__ A, const u16* __restrict__ B,
                          const float* __restrict__ bias, const float* __restrict__ resIn,
                          float* __restrict__ resOut, u16* __restrict__ outB,
                          int M, int Nout, int K) {
    __shared__ u16 As[64 * 64];
    __shared__ u16 Bs[64 * 64];
    const int m0 = blockIdx.y * 64, n0 = blockIdx.x * 64;
    const int t = threadIdx.x;
    const int wave = t >> 6, lane = t & 63;
    const int wm = (wave & 1) * 32, wn = (wave >> 1) * 32;
    const int sr = t >> 3;
    const int sc = ((((t & 7) - (t >> 3)) & 7)) * 8;    // swizzled global chunk
    const int fr = lane & 15, g0 = lane >> 4;

    floatx4 acc[2][2] = {};
    const u16* ag0 = A + (size_t)(m0 + sr) * K + sc;
    const u16* ag1 = A + (size_t)(m0 + 32 + sr) * K + sc;
    const u16* bg0 = B + (size_t)(n0 + sr) * K + sc;
    const u16* bg1 = B + (size_t)(n0 + 32 + sr) * K + sc;
    u16* as0 = As + t * 8;
    u16* as1 = As + 32 * 64 + t * 8;
    u16* bs0 = Bs + t * 8;
    u16* bs1 = Bs + 32 * 64 + t * 8;

    for (int k0 = 0; k0 < K; k0 += 64) {
        __syncthreads();
        gld_lds16(ag0 + k0, as0);
        gld_lds16(ag1 + k0, as1);
        gld_lds16(bg0 + k0, bs0);
        gld_lds16(bg1 + k0, bs1);
        __syncthreads();
#pragma unroll
        for (int h = 0; h < 2; h++) {
            const int fo = (((h << 2) + g0 + fr) & 7) << 3;   // swizzled read offset
            short8 af[2], bf[2];
#pragma unroll
            for (int i = 0; i < 2; i++) af[i] = *(const short8*)&As[(wm + 16 * i + fr) * 64 + fo];
#pragma unroll
            for (int j = 0; j < 2; j++) bf[j] = *(const short8*)&Bs[(wn + 16 * j + fr) * 64 + fo];
#pragma unroll
            for (int i = 0; i < 2; i++)
#pragma unroll
                for (int j = 0; j < 2; j++)
                    acc[i][j] = __builtin_amdgcn_mfma_f32_16x16x32_bf16(af[i], bf[j], acc[i][j], 0, 0, 0);
        }
    }

    const int er = (lane >> 4) * 4, ec = lane & 15;
#pragma unroll
    for (int i = 0; i < 2; i++) {
#pragma unroll
        for (int j = 0; j < 2; j++) {
            int col = n0 + wn + 16 * j + ec;
            float bsv = bias[col];
#pragma unroll
            for (int r = 0; r < 4; r++) {
                int row = m0 + wm + 16 * i + er + r;
                float val = acc[i][j][r] + bsv;
                if (MODE == 1) val = 0.5f * val * (1.0f + erff(val * 0.70710678118654752f));
                if (MODE == 2) {
                    resOut[(size_t)row * Nout + col] = resIn[(size_t)row * Nout + col] + val;
                } else {
                    outB[(size_t)row * Nout + col] = f2bf(val);
                }
            }
        }
    }
}

// ---------------------------------------------------------------- 128x64 QKV GEMM, BK=64, swizzled
// Output: Q -> f16 buffer q[N,512]; K/V -> fp8 interleaved kv8[N][64 groups][K8|V8]
__launch_bounds__(256)
__global__ void gemm_qkv(const u16* __restrict__ A, const u16* __restrict__ B,
                         const float* __restrict__ bias, u16* __restrict__ qOut,
                         u8* __restrict__ kv8) {
    __shared__ u16 As[128 * 64];   // 16 KB
    __shared__ u16 Bs[64 * 64];    // 8 KB
    const int m0 = blockIdx.y * 128, n0 = blockIdx.x * 64;
    const int t = threadIdx.x;
    const int wave = t >> 6, lane = t & 63;
    const int wm = (wave & 1) * 64, wn = (wave >> 1) * 32;
    const int sr = t >> 3;
    const int sc = ((((t & 7) - (t >> 3)) & 7)) * 8;
    const int fr = lane & 15, g0 = lane >> 4;

    floatx4 acc[4][2] = {};
    const u16* agp[4];
    u16* asp[4];
#pragma unroll
    for (int u = 0; u < 4; u++) {
        agp[u] = A + (size_t)(m0 + 32 * u + sr) * DD + sc;
        asp[u] = As + u * (32 * 64) + t * 8;
    }
    const u16* bg0 = B + (size_t)(n0 + sr) * DD + sc;
    const u16* bg1 = B + (size_t)(n0 + 32 + sr) * DD + sc;
    u16* bs0 = Bs + t * 8;
    u16* bs1 = Bs + 32 * 64 + t * 8;

    for (int k0 = 0; k0 < DD; k0 += 64) {
        __syncthreads();
#pragma unroll
        for (int u = 0; u < 4; u++) gld_lds16(agp[u] + k0, asp[u]);
        gld_lds16(bg0 + k0, bs0);
        gld_lds16(bg1 + k0, bs1);
        __syncthreads();
#pragma unroll
        for (int h = 0; h < 2; h++) {
            const int fo = (((h << 2) + g0 + fr) & 7) << 3;
            short8 af[4], bf[2];
#pragma unroll
            for (int i = 0; i < 4; i++) af[i] = *(const short8*)&As[(wm + 16 * i + fr) * 64 + fo];
#pragma unroll
            for (int j = 0; j < 2; j++) bf[j] = *(const short8*)&Bs[(wn + 16 * j + fr) * 64 + fo];
#pragma unroll
            for (int i = 0; i < 4; i++)
#pragma unroll
                for (int j = 0; j < 2; j++)
                    acc[i][j] = __builtin_amdgcn_mfma_f32_16x16x32_bf16(af[i], bf[j], acc[i][j], 0, 0, 0);
        }
    }

    const int er = (lane >> 4) * 4, ec = lane & 15;
    const int bx = blockIdx.x;
#pragma unroll
    for (int j = 0; j < 2; j++) {
        int col = n0 + wn + 16 * j + ec;
        float bsv = bias[col];
#pragma unroll
        for (int i = 0; i < 4; i++) {
#pragma unroll
            for (int r = 0; r < 4; r++) {
                int row = m0 + wm + 16 * i + er + r;
                float val = acc[i][j][r] + bsv;
                if (bx < 8) {                         // Q -> f16
                    qOut[(size_t)row * 512 + col] = f2h(val);
                } else if (bx < 16) {                 // K -> fp8, group-interleaved
                    int cc = col - 512;
                    kv8[(size_t)row * 1024 + 16 * (cc >> 3) + (cc & 7)] = f2fp8(val);
                } else {                              // V -> fp8
                    int cc = col - 1024;
                    kv8[(size_t)row * 1024 + 16 * (cc >> 3) + 8 + (cc & 7)] = f2fp8(val);
                }
            }
        }
    }
}

// ---------------------------------------------------------------- sparse attention (fp8 KV, f16 Q)
// 2 waves/query, 4 queries/block; idx in LDS; single 16B KV load per key; 2-deep prefetch
__global__ void sparse_attn(const u16* __restrict__ q, const u8* __restrict__ kv8,
                            const int* __restrict__ idx, const int* __restrict__ cnt,
                            u16* __restrict__ o) {
    int t = threadIdx.x;
    int wave = t >> 6, lane = t & 63;
    int qslot = wave >> 1, half = wave & 1;
    int qi = blockIdx.x * 4 + qslot;
    __shared__ float obuf[4][64][8];
    __shared__ float sbuf[4][64];
    __shared__ int sidx[4][CAP];

    int c = cnt[qi];
    const int* ir = idx + qi * CAP;
    for (int j = t & 127; j < c; j += 128) sidx[qslot][j] = ir[j];

    half8v qv = *(const half8v*)(q + (size_t)qi * 512 + lane * 8);
    float qf[8];
#pragma unroll
    for (int e = 0; e < 8; e++) qf[e] = (float)qv[e];
    __syncthreads();

    float sum = 0.f, oa[8] = {};
    int j = half;
    int4 kvp;
    if (j < c) kvp = *(const int4*)(kv8 + (size_t)sidx[qslot][j] * 1024 + lane * 16);
    while (j < c) {
        int jn = j + 2;
        int4 kvn;
        {
            int kjn = (jn < c) ? sidx[qslot][jn] : 0;
            kvn = *(const int4*)(kv8 + (size_t)kjn * 1024 + lane * 16);
        }
        float kd[8], vd[8];
#if __has_builtin(__builtin_amdgcn_cvt_pk_f32_fp8)
        {
            f32x2 p0 = __builtin_amdgcn_cvt_pk_f32_fp8(kvp.x, false);
            f32x2 p1 = __builtin_amdgcn_cvt_pk_f32_fp8(kvp.x, true);
            f32x2 p2 = __builtin_amdgcn_cvt_pk_f32_fp8(kvp.y, false);
            f32x2 p3 = __builtin_amdgcn_cvt_pk_f32_fp8(kvp.y, true);
            kd[0] = p0.x; kd[1] = p0.y; kd[2] = p1.x; kd[3] = p1.y;
            kd[4] = p2.x; kd[5] = p2.y; kd[6] = p3.x; kd[7] = p3.y;
            f32x2 p4 = __builtin_amdgcn_cvt_pk_f32_fp8(kvp.z, false);
            f32x2 p5 = __builtin_amdgcn_cvt_pk_f32_fp8(kvp.z, true);
            f32x2 p6 = __builtin_amdgcn_cvt_pk_f32_fp8(kvp.w, false);
            f32x2 p7 = __builtin_amdgcn_cvt_pk_f32_fp8(kvp.w, true);
            vd[0] = p4.x; vd[1] = p4.y; vd[2] = p5.x; vd[3] = p5.y;
            vd[4] = p6.x; vd[5] = p6.y; vd[6] = p7.x; vd[7] = p7.y;
        }
#else
        {
            const u8* bp = (const u8*)&kvp;
#pragma unroll
            for (int e = 0; e < 8; e++) { kd[e] = fp82f_sw(bp[e]); vd[e] = fp82f_sw(bp[8 + e]); }
        }
#endif
        float d = 0.f;
#pragma unroll
        for (int e = 0; e < 8; e++) d = fmaf(qf[e], kd[e], d);
        d += __shfl_xor(d, 1);
        d += __shfl_xor(d, 2);
        d += __shfl_xor(d, 4);
        d += __shfl_xor(d, 8);
        float p = __expf(d * SCALE);
        sum += p;
#pragma unroll
        for (int e = 0; e < 8; e++) oa[e] = fmaf(p, vd[e], oa[e]);
        kvp = kvn;
        j = jn;
    }

    if (half == 1) {
#pragma unroll
        for (int e = 0; e < 8; e++) obuf[qslot][lane][e] = oa[e];
        sbuf[qslot][lane] = sum;
    }
    __syncthreads();
    if (half == 0) {
        sum += sbuf[qslot][lane];
        float inv = 1.0f / sum;
        ushort8 ov;
#pragma unroll
        for (int e = 0; e < 8; e++) ov[e] = f2bf((oa[e] + obuf[qslot][lane][e]) * inv);
        *(ushort8*)(o + (size_t)qi * 512 + lane * 8) = ov;
    }
}

// ---------------------------------------------------------------- launch
extern "C" void kernel_launch(void* const* d_in, const int* in_sizes, int n_in,
                              void* d_out, int out_size, void* d_ws, size_t ws_size,
                              hipStream_t stream) {
    const float* nfeat = (const float*)d_in[0];
    const int*   mask  = (const int*)d_in[1];
    const float* ln1_g = (const float*)d_in[2];
    const float* ln1_b = (const float*)d_in[3];
    const float* bo    = (const float*)d_in[11];
    const float* ln2_g = (const float*)d_in[12];
    const float* ln2_b = (const float*)d_in[13];
    const float* fc1_b = (const float*)d_in[15];
    const float* fc2_b = (const float*)d_in[17];

    const size_t ND = (size_t)NN * DD;
    float* x    = (float*)d_ws;                      // 8 MB
    u16*   h    = (u16*)(x + ND);                    // 4 MB
    u16*   q    = h + ND;                            // 4 MB (f16)
    u8*    kv8  = (u8*)(q + ND);                     // 4 MB (fp8 K|V interleaved)
    u16*   o    = (u16*)(kv8 + (size_t)NN * 1024);   // 4 MB
    u16*   m1   = o + ND;                            // 4 MB
    u16*   wc   = m1 + ND;                           // 12 MB
    float* bcat = (float*)(wc + (size_t)12 * DD * DD);
    int*   idx  = (int*)(bcat + 2 * 1536);           // 4 MB
    int*   cnt  = idx + (size_t)NN * CAP;

    W6 w6;
    w6.w[0] = (const float*)d_in[4];  w6.w[1] = (const float*)d_in[6];
    w6.w[2] = (const float*)d_in[8];  w6.w[3] = (const float*)d_in[10];
    w6.w[4] = (const float*)d_in[14]; w6.w[5] = (const float*)d_in[16];
    w6.bq = (const float*)d_in[5]; w6.bk = (const float*)d_in[7]; w6.bv = (const float*)d_in[9];
    cast_weights<<<192, 256, 0, stream>>>(w6, wc, bcat);
    build_idx_kernel<<<NN, 256, 0, stream>>>(mask, idx, cnt);

    const size_t SS = (size_t)DD * DD;
    for (int l = 0; l < 2; l++) {
        size_t bOff = (size_t)l * DD;
        u16* wl = wc + (size_t)l * 6 * SS;
        const float* xin = (l == 0) ? nfeat : x;
        float* fc2_dst = (l == 1) ? (float*)d_out : x;

        ln_kernel<<<NN / 4, 256, 0, stream>>>(xin, ln1_g + bOff, ln1_b + bOff, h);
        gemm_qkv<<<dim3(24, 32), 256, 0, stream>>>(h, wl, bcat + l * 1536, q, kv8);
        sparse_attn<<<NN / 4, 512, 0, stream>>>(q, kv8, idx, cnt, o);
        gemm_bf16<2><<<dim3(8, 64), 256, 0, stream>>>(o, wl + 3 * SS, bo + bOff,
                                                      xin, x, nullptr, NN, DD, DD);
        ln_kernel<<<NN / 4, 256, 0, stream>>>(x, ln2_g + bOff, ln2_b + bOff, h);
        gemm_bf16<1><<<dim3(8, 64), 256, 0, stream>>>(h, wl + 4 * SS, fc1_b + bOff,
                                                      nullptr, nullptr, m1, NN, FF, DD);
        gemm_bf16<2><<<dim3(8, 64), 256, 0, stream>>>(m1, wl + 5 * SS, fc2_b + bOff,
                                                      x, fc2_dst, nullptr, NN, DD, FF);
    }
}